// Round 14
// baseline (443.000 us; speedup 1.0000x reference)
//
#include <hip/hip_runtime.h>
#include <hip/hip_bf16.h>

#define NHEAD 34
#define HDIM  100
#define NNODE 200
#define NBATCH 32
#define EPSV 1e-20f

typedef __attribute__((ext_vector_type(8))) short bf16x8;
typedef __attribute__((ext_vector_type(4))) float f32x4;
typedef __attribute__((ext_vector_type(16))) float f32x16;
typedef __attribute__((ext_vector_type(4))) unsigned int ux4;

// native RNE float->bf16 (compiler emits v_cvt_pk_bf16_f32 for adjacent pairs)
__device__ inline unsigned short bf16rne(float x) {
    return __bfloat16_as_ushort(__float2bfloat16(x));
}
__device__ inline float bf16tof(unsigned short h) {
    unsigned u = ((unsigned)h) << 16;
    return __builtin_bit_cast(float, u);
}

// RNE 2-way split (residual <= ~2^-17|x|)
__device__ inline void split2s(float x, unsigned short& h0, unsigned short& h1) {
    h0 = bf16rne(x);
    h1 = bf16rne(x - bf16tof(h0));
}
__device__ inline void split2_pack8(const float* v, bf16x8& a0, bf16x8& a1) {
    #pragma unroll
    for (int j = 0; j < 8; j++) {
        unsigned short h0, h1; split2s(v[j], h0, h1);
        a0[j] = (short)h0; a1[j] = (short)h1;
    }
}

// 8 mask bits -> bf16x8 of 0.0/1.0
__device__ inline bf16x8 afrag_bits(unsigned byte) {
    ux4 p;
    #pragma unroll
    for (int r = 0; r < 4; r++) {
        p[r] = ((byte >> (2 * r)) & 1u) * 0x3F80u + ((byte >> (2 * r + 1)) & 1u) * 0x3F800000u;
    }
    return __builtin_bit_cast(bf16x8, p);
}

// ---------------------------------------------------------------------------
// Bitmask prepass: A (0/1 fp32, 174 MB) -> 4 u64 per row (256 bits, 7 MB).
__global__ __launch_bounds__(1024) void a_bitmask(const float* __restrict__ A,
                                                  unsigned long long* __restrict__ bm) {
    int row = blockIdx.x * 16 + (threadIdx.x >> 6);
    int lane = threadIdx.x & 63;
    if (row >= NBATCH * NHEAD * NNODE) return;
    const float* Ar = A + (size_t)row * NNODE;
    unsigned long long w0 = __ballot(Ar[lane] != 0.0f);
    unsigned long long w1 = __ballot(Ar[64 + lane] != 0.0f);
    unsigned long long w2 = __ballot(Ar[128 + lane] != 0.0f);
    unsigned long long w3 = __ballot(lane < 8 ? (Ar[192 + lane] != 0.0f) : false);
    if (lane == 0) {
        unsigned long long* p = bm + (size_t)row * 4;
        p[0] = w0; p[1] = w1; p[2] = w2; p[3] = w3;
    }
}

// ---------------------------------------------------------------------------
// Merged W/X split prepass (2 planes each).
//   blocks 0..67  : wfr[fw][frag=nt*4+ks][2][512] from w_vs
//   blocks 68..99 : xfr[b][frag=mt*4+ks][2][512] from X*start
__global__ __launch_bounds__(256) void wx_split(const float* __restrict__ wv,
                                                const float* __restrict__ X,
                                                const float* __restrict__ start,
                                                short* __restrict__ wfr,
                                                short* __restrict__ xfr) {
    int blk = blockIdx.x;
    if (blk < 68) {
        int fw = blk;
        const float* W = wv + (size_t)(fw / 34) * 350000 + (size_t)(fw % 34) * 10000;
        for (int s0 = threadIdx.x; s0 < 28 * 64; s0 += 256) {
            int frag = s0 >> 6;
            int l = s0 & 63;
            int nt = frag >> 2, ks = frag & 3;
            int n = nt * 16 + (l & 15);
            int kb = ks * 32 + ((l >> 4) << 3);
            float v[8];
            #pragma unroll
            for (int j = 0; j < 8; j++) {
                int k = kb + j;
                v[j] = (k < 100 && n < 100) ? W[k * 100 + n] : 0.0f;
            }
            bf16x8 p0, p1;
            split2_pack8(v, p0, p1);
            size_t base = (((size_t)fw * 28 + frag) * 2) * 512 + l * 8;
            *(bf16x8*)&wfr[base]       = p0;
            *(bf16x8*)&wfr[base + 512] = p1;
        }
    } else {
        int b = blk - 68;
        const float* Xb = X + (size_t)b * 20000;
        const float* st = start + (size_t)b * NNODE;
        for (int s0 = threadIdx.x; s0 < 52 * 64; s0 += 256) {
            int frag = s0 >> 6;
            int l = s0 & 63;
            int mt = frag >> 2, ks = frag & 3;
            int row = mt * 16 + (l & 15);
            int kb = ks * 32 + ((l >> 4) << 3);
            float sc = (row < 200) ? st[row] : 0.0f;
            float v[8];
            #pragma unroll
            for (int j = 0; j < 8; j++) {
                int k = kb + j;
                v[j] = (row < 200 && k < 100) ? Xb[row * 100 + k] * sc : 0.0f;
            }
            bf16x8 p0, p1;
            split2_pack8(v, p0, p1);
            size_t base = (((size_t)b * 52 + frag) * 2) * 512 + l * 8;
            *(bf16x8*)&xfr[base]       = p0;
            *(bf16x8*)&xfr[base + 512] = p1;
        }
    }
}

// ---------------------------------------------------------------------------
// Fused per-(b,f,col-half) kernel, 1024 threads = 16 waves, 2 blocks/CU:
//   ch=0 owns output cols 0..63; ch=1 owns cols 64..99 + Dh (dvec col 100).
//   Phase 1: Zh cols of this half -> LDS as 2 bf16 planes [col][n] (R12 map).
//   Phase 2: A @ Zh via 32x32x16 MFMA (A from bitmask), 1 tile/wave,
//            ks-loop fully unrolled.
//   zpl rows padded to 220 shorts (110 words, gcd(14,32)=2): phase-2
//   ds_read_b128 2-way (free, m136); phase-1 short4 writes conflict-free.
//   Output staged via reused LDS -> coalesced float4 streams.
//   Bijective XCD swizzle (2176 = 8 x 272): ch-pairs + ~4 b's per XCD.
template <int T>
__global__ __launch_bounds__(1024, 8) void fused_zha(
    const unsigned* __restrict__ bm32,
    const short* __restrict__ xfr,      // T=0: [b][52][2][512]
    const float* __restrict__ Sfp,      // T=1: [b][f][200][100] fp32
    const short* __restrict__ wfr_t,    // [f][28][2][512]
    const float* __restrict__ uni,
    const float* __restrict__ start,    // T=0: dvec = start*uni
    const float* __restrict__ dvec_g,   // T=1: [b][f][200]
    float* __restrict__ Zout, float* __restrict__ Dh)
{
    // bijective XCD swizzle: 2176 blocks, 8 XCDs, 272 per XCD
    int g = blockIdx.y * 68 + blockIdx.x;
    int wk = (g & 7) * 272 + (g >> 3);
    int b = wk / 68;
    int rem = wk - b * 68;
    int f = rem >> 1, ch = rem & 1;
    size_t bf = (size_t)b * NHEAD + f;
    int tid = threadIdx.x;
    int l = tid & 63, w = tid >> 6;

    __shared__ __align__(16) short zpl[2][64][220];   // 56,320 B (padded rows)
    __shared__ unsigned mkl[8][225];                  //  7,200 B

    // ---- masks into LDS (transposed: [word][m]) ----
    const unsigned* bmw = bm32 + bf * 1600;           // [m][8] u32
    for (int idx = tid; idx < 1600; idx += 1024) mkl[idx & 7][idx >> 3] = bmw[idx];
    if (tid < 200) mkl[tid / 25][200 + tid % 25] = 0u;

    float u = uni[b * NHEAD + f];

    if (ch == 1) {
        // dvec column: global col 100 = local 36
        if (tid < 200) {
            float dv;
            if constexpr (T == 0) dv = start[b * NNODE + tid] * u;
            else                  dv = dvec_g[bf * NNODE + tid];
            unsigned short h0, h1; split2s(dv, h0, h1);
            zpl[0][36][tid] = (short)h0; zpl[1][36][tid] = (short)h1;
        } else if (tid < 232) {       // zero rows 200..215 of dvec col (NaN guard)
            int r = 200 + ((tid - 200) & 15), s = (tid - 200) >> 4;
            zpl[s][36][r] = 0;
        }
    }

    // ---- phase 1: W-GEMM for this half's nt tiles (1 m-tile per wave) ----
    const short* WF = wfr_t + (size_t)f * 28 * 2 * 512;
    int ntb = ch ? 4 : 0, nte = ch ? 7 : 4;
    int coff = ch * 64;
    for (int mt = w; mt < 13; mt += 16) {
        bf16x8 A0[4], A1[4];
        if constexpr (T == 0) {
            const short* AG = xfr + ((size_t)b * 52 + mt * 4) * 2 * 512;
            #pragma unroll
            for (int ks = 0; ks < 4; ks++) {
                A0[ks] = *(const bf16x8*)&AG[(ks * 2 + 0) * 512 + l * 8];
                A1[ks] = *(const bf16x8*)&AG[(ks * 2 + 1) * 512 + l * 8];
            }
        } else {
            const float* S = Sfp + bf * 20000;
            int row = mt * 16 + (l & 15);
            bool rok = row < 200;
            #pragma unroll
            for (int ks = 0; ks < 4; ks++) {
                int kb = ks * 32 + ((l >> 4) << 3);
                float4 z4 = make_float4(0.f, 0.f, 0.f, 0.f);
                float4 v0 = (rok && kb < 100)     ? *(const float4*)&S[row * 100 + kb]     : z4;
                float4 v1 = (rok && kb + 4 < 100) ? *(const float4*)&S[row * 100 + kb + 4] : z4;
                float vv[8] = {v0.x, v0.y, v0.z, v0.w, v1.x, v1.y, v1.z, v1.w};
                split2_pack8(vv, A0[ks], A1[ks]);
            }
        }
        for (int nt = ntb; nt < nte; nt++) {
            f32x4 acc = {0.f, 0.f, 0.f, 0.f};
            #pragma unroll
            for (int ks = 0; ks < 4; ks++) {
                const short* wp = &WF[(size_t)((nt * 4 + ks) * 2) * 512 + l * 8];
                bf16x8 B0 = *(const bf16x8*)&wp[0];
                bf16x8 B1 = *(const bf16x8*)&wp[512];
                acc = __builtin_amdgcn_mfma_f32_16x16x32_bf16(A0[ks], B0, acc, 0, 0, 0);
                acc = __builtin_amdgcn_mfma_f32_16x16x32_bf16(A1[ks], B0, acc, 0, 0, 0);
                acc = __builtin_amdgcn_mfma_f32_16x16x32_bf16(A0[ks], B1, acc, 0, 0, 0);
            }
            // D layout: col = l&15, row = (l>>4)*4 + reg   [m89]
            int c = nt * 16 + (l & 15);
            if (c < 100) {
                int nb = mt * 16 + ((l >> 4) << 2);
                short4 q0, q1;
                #pragma unroll
                for (int r = 0; r < 4; r++) {
                    unsigned short h0, h1; split2s(acc[r] * u, h0, h1);
                    ((short*)&q0)[r] = (short)h0;
                    ((short*)&q1)[r] = (short)h1;
                }
                *(short4*)&zpl[0][c - coff][nb] = q0;
                *(short4*)&zpl[1][c - coff][nb] = q1;
            }
        }
    }
    __syncthreads();

    // ---- phase 2: A @ Zh, 1 32x32 tile per wave (14 active waves) ----
    int cl = l & 31, kg = l >> 5;
    int mt2 = w >> 1, cg = w & 1;          // mt2 in 0..6, cg in 0..1
    int myl = cg * 32 + cl;                // local col 0..63
    bool act = (w < 14);

    f32x16 acc2;
    #pragma unroll
    for (int i = 0; i < 16; i++) acc2[i] = 0.f;

    if (act) {
        const short* z0base = &zpl[0][myl][kg * 8];
        const short* z1base = &zpl[1][myl][kg * 8];
        const unsigned* mrow = &mkl[0][mt2 * 32 + cl];
        int shmt0 = (kg << 3);
        #pragma unroll
        for (int ks = 0; ks < 13; ks++) {
            bf16x8 z0 = *(const bf16x8*)&z0base[ks * 16];
            bf16x8 z1 = *(const bf16x8*)&z1base[ks * 16];
            unsigned word = mrow[(ks >> 1) * 225];
            unsigned byte = (word >> (((ks & 1) << 4) | shmt0)) & 0xFFu;
            bf16x8 af = afrag_bits(byte);
            acc2 = __builtin_amdgcn_mfma_f32_32x32x16_bf16(af, z0, acc2, 0, 0, 0);
            acc2 = __builtin_amdgcn_mfma_f32_32x32x16_bf16(af, z1, acc2, 0, 0, 0);
        }
    }
    __syncthreads();                        // zpl reads done; reuse as fp32 stage

    float* zs = (float*)&zpl[0][0][0];      // [200][68] = 54,400 B
    if (act) {
        int myg = coff + myl;
        if (myg <= 100) {
            #pragma unroll
            for (int r = 0; r < 16; r++) {
                int m = mt2 * 32 + (r & 3) + ((r >> 2) << 3) + (kg << 2);
                if (m < 200) zs[m * 68 + myl] = acc2[r];
            }
        }
    }
    __syncthreads();

    // ---- stream out (coalesced float4) ----
    float* Zob = Zout + bf * 20000;
    if (ch == 0) {
        for (int idx = tid; idx < 3200; idx += 1024) {
            int m = idx >> 4, c4 = idx & 15;
            *(float4*)&Zob[m * 100 + c4 * 4] = *(const float4*)&zs[m * 68 + c4 * 4];
        }
    } else {
        float* Dhb = Dh + bf * NNODE;
        for (int idx = tid; idx < 2000; idx += 1024) {
            int m = idx / 10, c4 = idx % 10;
            if (c4 < 9) *(float4*)&Zob[m * 100 + 64 + c4 * 4] = *(const float4*)&zs[m * 68 + c4 * 4];
            else Dhb[m] = zs[m * 68 + 36];
        }
    }
}

// ---------------------------------------------------------------------------
// out0 GEMM, row-chunked: out[b, rows 50c..50c+49, :] = rs0 .* (Zsum0 @ Wi1)
__global__ __launch_bounds__(256) void out0_gemm(
    const float* __restrict__ src, const float* __restrict__ W,
    const float* __restrict__ rowscale, float* __restrict__ dst)
{
    int c = blockIdx.x, b = blockIdx.y;
    const float* S = src + (size_t)b * 20000;
    float* Dst = dst + (size_t)b * 20000;

    __shared__ __align__(16) float wl[10000];
    __shared__ __align__(16) float xl[5000];

    int tid = threadIdx.x;
    for (int idx = tid; idx < 10000; idx += 256) wl[idx] = W[idx];
    int base = c * 5000;
    for (int idx = tid; idx < 5000; idx += 256) xl[idx] = S[base + idx];
    __syncthreads();

    int q = tid % 25;
    int ty = tid / 25;
    if (ty < 10) {
        float4 acc[5];
        #pragma unroll
        for (int r = 0; r < 5; r++) acc[r] = make_float4(0.f, 0.f, 0.f, 0.f);
        #pragma unroll 2
        for (int i = 0; i < 100; i++) {
            float4 w4 = *(const float4*)&wl[i * 100 + q * 4];
            #pragma unroll
            for (int r = 0; r < 5; r++) {
                float x = xl[(ty + 10 * r) * 100 + i];
                acc[r].x += x * w4.x; acc[r].y += x * w4.y;
                acc[r].z += x * w4.z; acc[r].w += x * w4.w;
            }
        }
        #pragma unroll
        for (int r = 0; r < 5; r++) {
            int n = c * 50 + ty + 10 * r;
            float sc = rowscale[b * NNODE + n];
            float4 o4 = make_float4(acc[r].x * sc, acc[r].y * sc, acc[r].z * sc, acc[r].w * sc);
            *(float4*)&Dst[n * 100 + q * 4] = o4;
        }
    }
}

// ---------------------------------------------------------------------------
// dvec1[b,g,n] = uni[b,g] * sum_f Dh0[b,f,n] * trans[b,f,g]
// rs0[b,n]    = end / (end * sum_f Dh0[b,f,n] + EPS)
__global__ void dmix_rs(const float* __restrict__ Dh0, const float* __restrict__ trans,
                        const float* __restrict__ uni, const float* __restrict__ endat,
                        float* __restrict__ dvec1, float* __restrict__ rs0) {
    int b = blockIdx.x;
    __shared__ float tl[NHEAD * NHEAD];
    for (int idx = threadIdx.x; idx < NHEAD * NHEAD; idx += 256) tl[idx] = trans[b * NHEAD * NHEAD + idx];
    __syncthreads();
    int n = threadIdx.x;
    if (n < NNODE) {
        float dh[NHEAD];
        float s = 0.f;
        #pragma unroll
        for (int f = 0; f < NHEAD; f++) { dh[f] = Dh0[((size_t)b * NHEAD + f) * NNODE + n]; s += dh[f]; }
        float e = endat[b * NNODE + n];
        rs0[b * NNODE + n] = e / (e * s + EPSV);
        #pragma unroll
        for (int g = 0; g < NHEAD; g++) {
            float acc = 0.f;
            #pragma unroll
            for (int f = 0; f < NHEAD; f++) acc += dh[f] * tl[f * NHEAD + g];
            dvec1[((size_t)b * NHEAD + g) * NNODE + n] = uni[b * NHEAD + g] * acc;
        }
    }
}

// ---------------------------------------------------------------------------
// Head mix + f-sum (float2/lane)
__global__ __launch_bounds__(256) void hmix(
    const float* __restrict__ Zsrc, const float* __restrict__ trans,
    float* __restrict__ Zdst, float* __restrict__ Zsum)
{
    int b = blockIdx.y;
    int c2 = blockIdx.x * 256 + threadIdx.x;   // float2 index, 10000 per b
    __shared__ __align__(8) float tl[NHEAD * NHEAD];
    for (int idx = threadIdx.x; idx < NHEAD * NHEAD; idx += 256) tl[idx] = trans[b * NHEAD * NHEAD + idx];
    __syncthreads();
    if (c2 >= 10000) return;
    const float2* Zb = (const float2*)(Zsrc + (size_t)b * NHEAD * 20000) + c2;
    float2 acc[NHEAD];
    #pragma unroll
    for (int g = 0; g < NHEAD; g++) acc[g] = make_float2(0.f, 0.f);
    float2 s = make_float2(0.f, 0.f);
    for (int f = 0; f < NHEAD; f++) {
        float2 vf = Zb[(size_t)f * 10000];
        s.x += vf.x; s.y += vf.y;
        const float2* row = (const float2*)&tl[f * NHEAD];
        #pragma unroll
        for (int gq = 0; gq < 17; gq++) {
            float2 t2 = row[gq];
            acc[2 * gq].x     += vf.x * t2.x; acc[2 * gq].y     += vf.y * t2.x;
            acc[2 * gq + 1].x += vf.x * t2.y; acc[2 * gq + 1].y += vf.y * t2.y;
        }
    }
    ((float2*)(Zsum + (size_t)b * 20000))[c2] = s;
    float2* Zd = (float2*)(Zdst + (size_t)b * NHEAD * 20000) + c2;
    #pragma unroll
    for (int g = 0; g < NHEAD; g++) Zd[(size_t)g * 10000] = acc[g];
}

// ---------------------------------------------------------------------------
// out1[b,n,i] = rs1[b,n] * sum_g Zacc[b,g,n,i]; rs1 computed inline from Dh1.
__global__ void fsum_out(const float* __restrict__ Zacc, const float* __restrict__ Dh1,
                         const float* __restrict__ endat, float* __restrict__ out) {
    int idx = blockIdx.x * 256 + threadIdx.x;   // float2 units
    if (idx >= NBATCH * 10000) return;
    int b = idx / 10000;
    int c2 = idx % 10000;
    const float2* Zb = (const float2*)(Zacc + (size_t)b * NHEAD * 20000) + c2;
    float2 s = make_float2(0.f, 0.f);
    #pragma unroll
    for (int g = 0; g < NHEAD; g++) {
        float2 v = Zb[(size_t)g * 10000];
        s.x += v.x; s.y += v.y;
    }
    int n = (c2 * 2) / 100;
    float ds = 0.f;
    #pragma unroll
    for (int f = 0; f < NHEAD; f++) ds += Dh1[((size_t)b * NHEAD + f) * NNODE + n];
    float e = endat[b * NNODE + n];
    float r = e / (e * ds + EPSV);
    s.x *= r; s.y *= r;
    ((float2*)out)[idx] = s;
}

// ---------------------------------------------------------------------------
extern "C" void kernel_launch(void* const* d_in, const int* in_sizes, int n_in,
                              void* d_out, int out_size, void* d_ws, size_t ws_size,
                              hipStream_t stream) {
    (void)in_sizes; (void)n_in;
    const float* X     = (const float*)d_in[0];
    const float* A     = (const float*)d_in[1];
    const float* start = (const float*)d_in[2];
    const float* endat = (const float*)d_in[3];
    const float* uni   = (const float*)d_in[4];
    const float* trans = (const float*)d_in[5];
    const float* wv    = (const float*)d_in[6];
    float* out = (float*)d_out;
    float* ws  = (float*)d_ws;

    size_t off = 0;
    unsigned long long* bm = (unsigned long long*)(ws); off += 1740800;  // 217600 rows * 4 u64
    float* buf1  = ws + off; off += 21760000;
    float* buf2  = ws + off; off += 21760000;
    float* Dh0   = ws + off; off += 217600;
    float* dvec1 = ws + off; off += 217600;
    float* Dh1   = ws + off; off += 217600;
    float* rs0   = ws + off; off += 6400;
    float* Zsum0 = ws + off; off += 640000;
    short* wfr   = (short*)(ws + off); off += 974848;   // 68*28*2*512 shorts
    short* xfr   = (short*)(ws + off); off += 851968;   // 32*52*2*512 shorts
    if (ws_size < off * sizeof(float)) {
        hipMemsetAsync(d_out, 0x7F, (size_t)out_size * sizeof(float), stream);
        return;
    }

    const float* Wi1 = wv + 690000;        // w_vs[1, 34]
    const short* wfr0 = wfr;
    const short* wfr1 = wfr + (size_t)34 * 28 * 2 * 512;
    const unsigned* bm32 = (const unsigned*)bm;

    dim3 gBF(NHEAD * 2, NBATCH);           // x = f*2 + col-half (pre-swizzle)

    // prepasses
    a_bitmask<<<(NBATCH * NHEAD * NNODE + 15) / 16, 1024, 0, stream>>>(A, bm);
    wx_split<<<100, 256, 0, stream>>>(wv, X, start, wfr, xfr);

    // t = 0 : fused W-GEMM + A-GEMM (dvec computed in-kernel)
    fused_zha<0><<<gBF, 1024, 0, stream>>>(bm32, xfr, nullptr, wfr0, uni, start, nullptr, buf2, Dh0);
    dmix_rs<<<NBATCH, 256, 0, stream>>>(Dh0, trans, uni, endat, dvec1, rs0);
    hmix<<<dim3(40, NBATCH), 256, 0, stream>>>(buf2, trans, buf1, Zsum0);    // buf1 = Zin1
    out0_gemm<<<dim3(4, NBATCH), 256, 0, stream>>>(Zsum0, Wi1, rs0, out);    // out[0]

    // t = 1
    fused_zha<1><<<gBF, 1024, 0, stream>>>(bm32, nullptr, buf1, wfr1, uni, nullptr, dvec1, buf2, Dh1);
    fsum_out<<<(NBATCH * 10000 + 255) / 256, 256, 0, stream>>>(buf2, Dh1, endat, out + 640000);
}

// Round 15
// 325.976 us; speedup vs baseline: 1.3590x; 1.3590x over previous
//
#include <hip/hip_runtime.h>
#include <hip/hip_bf16.h>

#define NHEAD 34
#define HDIM  100
#define NNODE 200
#define NBATCH 32
#define EPSV 1e-20f

typedef __attribute__((ext_vector_type(8))) short bf16x8;
typedef __attribute__((ext_vector_type(4))) float f32x4;
typedef __attribute__((ext_vector_type(16))) float f32x16;
typedef __attribute__((ext_vector_type(4))) unsigned int ux4;

// native RNE float->bf16 (compiler emits v_cvt_pk_bf16_f32 for adjacent pairs)
__device__ inline unsigned short bf16rne(float x) {
    return __bfloat16_as_ushort(__float2bfloat16(x));
}
__device__ inline float bf16tof(unsigned short h) {
    unsigned u = ((unsigned)h) << 16;
    return __builtin_bit_cast(float, u);
}

// RNE 2-way split (residual <= ~2^-17|x|)
__device__ inline void split2s(float x, unsigned short& h0, unsigned short& h1) {
    h0 = bf16rne(x);
    h1 = bf16rne(x - bf16tof(h0));
}
__device__ inline void split2_pack8(const float* v, bf16x8& a0, bf16x8& a1) {
    #pragma unroll
    for (int j = 0; j < 8; j++) {
        unsigned short h0, h1; split2s(v[j], h0, h1);
        a0[j] = (short)h0; a1[j] = (short)h1;
    }
}

// 8 mask bits -> bf16x8 of 0.0/1.0
__device__ inline bf16x8 afrag_bits(unsigned byte) {
    ux4 p;
    #pragma unroll
    for (int r = 0; r < 4; r++) {
        p[r] = ((byte >> (2 * r)) & 1u) * 0x3F80u + ((byte >> (2 * r + 1)) & 1u) * 0x3F800000u;
    }
    return __builtin_bit_cast(bf16x8, p);
}

// ---------------------------------------------------------------------------
// Bitmask prepass: A (0/1 fp32, 174 MB) -> 4 u64 per row (256 bits, 7 MB).
__global__ __launch_bounds__(1024) void a_bitmask(const float* __restrict__ A,
                                                  unsigned long long* __restrict__ bm) {
    int row = blockIdx.x * 16 + (threadIdx.x >> 6);
    int lane = threadIdx.x & 63;
    if (row >= NBATCH * NHEAD * NNODE) return;
    const float* Ar = A + (size_t)row * NNODE;
    unsigned long long w0 = __ballot(Ar[lane] != 0.0f);
    unsigned long long w1 = __ballot(Ar[64 + lane] != 0.0f);
    unsigned long long w2 = __ballot(Ar[128 + lane] != 0.0f);
    unsigned long long w3 = __ballot(lane < 8 ? (Ar[192 + lane] != 0.0f) : false);
    if (lane == 0) {
        unsigned long long* p = bm + (size_t)row * 4;
        p[0] = w0; p[1] = w1; p[2] = w2; p[3] = w3;
    }
}

// ---------------------------------------------------------------------------
// Merged W/X split prepass (2 planes each).
//   blocks 0..67  : wfr[fw][frag=nt*4+ks][2][512] from w_vs
//   blocks 68..99 : xfr[b][frag=mt*4+ks][2][512] from X*start
__global__ __launch_bounds__(256) void wx_split(const float* __restrict__ wv,
                                                const float* __restrict__ X,
                                                const float* __restrict__ start,
                                                short* __restrict__ wfr,
                                                short* __restrict__ xfr) {
    int blk = blockIdx.x;
    if (blk < 68) {
        int fw = blk;
        const float* W = wv + (size_t)(fw / 34) * 350000 + (size_t)(fw % 34) * 10000;
        for (int s0 = threadIdx.x; s0 < 28 * 64; s0 += 256) {
            int frag = s0 >> 6;
            int l = s0 & 63;
            int nt = frag >> 2, ks = frag & 3;
            int n = nt * 16 + (l & 15);
            int kb = ks * 32 + ((l >> 4) << 3);
            float v[8];
            #pragma unroll
            for (int j = 0; j < 8; j++) {
                int k = kb + j;
                v[j] = (k < 100 && n < 100) ? W[k * 100 + n] : 0.0f;
            }
            bf16x8 p0, p1;
            split2_pack8(v, p0, p1);
            size_t base = (((size_t)fw * 28 + frag) * 2) * 512 + l * 8;
            *(bf16x8*)&wfr[base]       = p0;
            *(bf16x8*)&wfr[base + 512] = p1;
        }
    } else {
        int b = blk - 68;
        const float* Xb = X + (size_t)b * 20000;
        const float* st = start + (size_t)b * NNODE;
        for (int s0 = threadIdx.x; s0 < 52 * 64; s0 += 256) {
            int frag = s0 >> 6;
            int l = s0 & 63;
            int mt = frag >> 2, ks = frag & 3;
            int row = mt * 16 + (l & 15);
            int kb = ks * 32 + ((l >> 4) << 3);
            float sc = (row < 200) ? st[row] : 0.0f;
            float v[8];
            #pragma unroll
            for (int j = 0; j < 8; j++) {
                int k = kb + j;
                v[j] = (row < 200 && k < 100) ? Xb[row * 100 + k] * sc : 0.0f;
            }
            bf16x8 p0, p1;
            split2_pack8(v, p0, p1);
            size_t base = (((size_t)b * 52 + frag) * 2) * 512 + l * 8;
            *(bf16x8*)&xfr[base]       = p0;
            *(bf16x8*)&xfr[base + 512] = p1;
        }
    }
}

// ---------------------------------------------------------------------------
// Fused per-(b,f,col-half) kernel, 1024 threads = 16 waves, 2 blocks/CU:
//   ch=0 owns output cols 0..63; ch=1 owns cols 64..99 + Dh (dvec col 100).
//   Phase 1: Zh cols of this half -> LDS as 2 bf16 planes [col][n].
//   Phase 2: A @ Zh via 32x32x16 MFMA (A from bitmask), 1 tile/wave,
//            ks-loop fully unrolled.
//   zpl rows = 216 shorts (432 B = 16-aligned; 4-way bank alias, measured
//   negligible: 675 conflict-cy/block). 220-pad broke b128 alignment (R14).
//   Output staged via reused LDS -> coalesced float4 streams.
//   Bijective XCD swizzle (2176 = 8 x 272): ch-pairs + ~4 b's per XCD.
template <int T>
__global__ __launch_bounds__(1024, 8) void fused_zha(
    const unsigned* __restrict__ bm32,
    const short* __restrict__ xfr,      // T=0: [b][52][2][512]
    const float* __restrict__ Sfp,      // T=1: [b][f][200][100] fp32
    const short* __restrict__ wfr_t,    // [f][28][2][512]
    const float* __restrict__ uni,
    const float* __restrict__ start,    // T=0: dvec = start*uni
    const float* __restrict__ dvec_g,   // T=1: [b][f][200]
    float* __restrict__ Zout, float* __restrict__ Dh)
{
    // bijective XCD swizzle: 2176 blocks, 8 XCDs, 272 per XCD
    int g = blockIdx.y * 68 + blockIdx.x;
    int wk = (g & 7) * 272 + (g >> 3);
    int b = wk / 68;
    int rem = wk - b * 68;
    int f = rem >> 1, ch = rem & 1;
    size_t bf = (size_t)b * NHEAD + f;
    int tid = threadIdx.x;
    int l = tid & 63, w = tid >> 6;

    __shared__ __align__(16) short zpl[2][64][216];   // 55,296 B
    __shared__ unsigned mkl[8][225];                  //  7,200 B

    // ---- masks into LDS (transposed: [word][m]) ----
    const unsigned* bmw = bm32 + bf * 1600;           // [m][8] u32
    for (int idx = tid; idx < 1600; idx += 1024) mkl[idx & 7][idx >> 3] = bmw[idx];
    if (tid < 200) mkl[tid / 25][200 + tid % 25] = 0u;

    float u = uni[b * NHEAD + f];

    if (ch == 1) {
        // dvec column: global col 100 = local 36
        if (tid < 200) {
            float dv;
            if constexpr (T == 0) dv = start[b * NNODE + tid] * u;
            else                  dv = dvec_g[bf * NNODE + tid];
            unsigned short h0, h1; split2s(dv, h0, h1);
            zpl[0][36][tid] = (short)h0; zpl[1][36][tid] = (short)h1;
        } else if (tid < 232) {       // zero rows 200..215 of dvec col (NaN guard)
            int r = 200 + ((tid - 200) & 15), s = (tid - 200) >> 4;
            zpl[s][36][r] = 0;
        }
    }

    // ---- phase 1: W-GEMM for this half's nt tiles (1 m-tile per wave) ----
    const short* WF = wfr_t + (size_t)f * 28 * 2 * 512;
    int ntb = ch ? 4 : 0, nte = ch ? 7 : 4;
    int coff = ch * 64;
    for (int mt = w; mt < 13; mt += 16) {
        bf16x8 A0[4], A1[4];
        if constexpr (T == 0) {
            const short* AG = xfr + ((size_t)b * 52 + mt * 4) * 2 * 512;
            #pragma unroll
            for (int ks = 0; ks < 4; ks++) {
                A0[ks] = *(const bf16x8*)&AG[(ks * 2 + 0) * 512 + l * 8];
                A1[ks] = *(const bf16x8*)&AG[(ks * 2 + 1) * 512 + l * 8];
            }
        } else {
            const float* S = Sfp + bf * 20000;
            int row = mt * 16 + (l & 15);
            bool rok = row < 200;
            #pragma unroll
            for (int ks = 0; ks < 4; ks++) {
                int kb = ks * 32 + ((l >> 4) << 3);
                float4 z4 = make_float4(0.f, 0.f, 0.f, 0.f);
                float4 v0 = (rok && kb < 100)     ? *(const float4*)&S[row * 100 + kb]     : z4;
                float4 v1 = (rok && kb + 4 < 100) ? *(const float4*)&S[row * 100 + kb + 4] : z4;
                float vv[8] = {v0.x, v0.y, v0.z, v0.w, v1.x, v1.y, v1.z, v1.w};
                split2_pack8(vv, A0[ks], A1[ks]);
            }
        }
        for (int nt = ntb; nt < nte; nt++) {
            f32x4 acc = {0.f, 0.f, 0.f, 0.f};
            #pragma unroll
            for (int ks = 0; ks < 4; ks++) {
                const short* wp = &WF[(size_t)((nt * 4 + ks) * 2) * 512 + l * 8];
                bf16x8 B0 = *(const bf16x8*)&wp[0];
                bf16x8 B1 = *(const bf16x8*)&wp[512];
                acc = __builtin_amdgcn_mfma_f32_16x16x32_bf16(A0[ks], B0, acc, 0, 0, 0);
                acc = __builtin_amdgcn_mfma_f32_16x16x32_bf16(A1[ks], B0, acc, 0, 0, 0);
                acc = __builtin_amdgcn_mfma_f32_16x16x32_bf16(A0[ks], B1, acc, 0, 0, 0);
            }
            // D layout: col = l&15, row = (l>>4)*4 + reg   [m89]
            int c = nt * 16 + (l & 15);
            if (c < 100) {
                int nb = mt * 16 + ((l >> 4) << 2);
                short4 q0, q1;
                #pragma unroll
                for (int r = 0; r < 4; r++) {
                    unsigned short h0, h1; split2s(acc[r] * u, h0, h1);
                    ((short*)&q0)[r] = (short)h0;
                    ((short*)&q1)[r] = (short)h1;
                }
                *(short4*)&zpl[0][c - coff][nb] = q0;
                *(short4*)&zpl[1][c - coff][nb] = q1;
            }
        }
    }
    __syncthreads();

    // ---- phase 2: A @ Zh, 1 32x32 tile per wave (14 active waves) ----
    int cl = l & 31, kg = l >> 5;
    int mt2 = w >> 1, cg = w & 1;          // mt2 in 0..6, cg in 0..1
    int myl = cg * 32 + cl;                // local col 0..63
    bool act = (w < 14);

    f32x16 acc2;
    #pragma unroll
    for (int i = 0; i < 16; i++) acc2[i] = 0.f;

    if (act) {
        const short* z0base = &zpl[0][myl][kg * 8];
        const short* z1base = &zpl[1][myl][kg * 8];
        const unsigned* mrow = &mkl[0][mt2 * 32 + cl];
        int shmt0 = (kg << 3);
        #pragma unroll
        for (int ks = 0; ks < 13; ks++) {
            bf16x8 z0 = *(const bf16x8*)&z0base[ks * 16];
            bf16x8 z1 = *(const bf16x8*)&z1base[ks * 16];
            unsigned word = mrow[(ks >> 1) * 225];
            unsigned byte = (word >> (((ks & 1) << 4) | shmt0)) & 0xFFu;
            bf16x8 af = afrag_bits(byte);
            acc2 = __builtin_amdgcn_mfma_f32_32x32x16_bf16(af, z0, acc2, 0, 0, 0);
            acc2 = __builtin_amdgcn_mfma_f32_32x32x16_bf16(af, z1, acc2, 0, 0, 0);
        }
    }
    __syncthreads();                        // zpl reads done; reuse as fp32 stage

    float* zs = (float*)&zpl[0][0][0];      // [200][68] = 54,400 B
    if (act) {
        int myg = coff + myl;
        if (myg <= 100) {
            #pragma unroll
            for (int r = 0; r < 16; r++) {
                int m = mt2 * 32 + (r & 3) + ((r >> 2) << 3) + (kg << 2);
                if (m < 200) zs[m * 68 + myl] = acc2[r];
            }
        }
    }
    __syncthreads();

    // ---- stream out (coalesced float4) ----
    float* Zob = Zout + bf * 20000;
    if (ch == 0) {
        for (int idx = tid; idx < 3200; idx += 1024) {
            int m = idx >> 4, c4 = idx & 15;
            *(float4*)&Zob[m * 100 + c4 * 4] = *(const float4*)&zs[m * 68 + c4 * 4];
        }
    } else {
        float* Dhb = Dh + bf * NNODE;
        for (int idx = tid; idx < 2000; idx += 1024) {
            int m = idx / 10, c4 = idx % 10;
            if (c4 < 9) *(float4*)&Zob[m * 100 + 64 + c4 * 4] = *(const float4*)&zs[m * 68 + c4 * 4];
            else Dhb[m] = zs[m * 68 + 36];
        }
    }
}

// ---------------------------------------------------------------------------
// out0 GEMM, row-chunked: out[b, rows 50c..50c+49, :] = rs0 .* (Zsum0 @ Wi1)
__global__ __launch_bounds__(256) void out0_gemm(
    const float* __restrict__ src, const float* __restrict__ W,
    const float* __restrict__ rowscale, float* __restrict__ dst)
{
    int c = blockIdx.x, b = blockIdx.y;
    const float* S = src + (size_t)b * 20000;
    float* Dst = dst + (size_t)b * 20000;

    __shared__ __align__(16) float wl[10000];
    __shared__ __align__(16) float xl[5000];

    int tid = threadIdx.x;
    for (int idx = tid; idx < 10000; idx += 256) wl[idx] = W[idx];
    int base = c * 5000;
    for (int idx = tid; idx < 5000; idx += 256) xl[idx] = S[base + idx];
    __syncthreads();

    int q = tid % 25;
    int ty = tid / 25;
    if (ty < 10) {
        float4 acc[5];
        #pragma unroll
        for (int r = 0; r < 5; r++) acc[r] = make_float4(0.f, 0.f, 0.f, 0.f);
        #pragma unroll 2
        for (int i = 0; i < 100; i++) {
            float4 w4 = *(const float4*)&wl[i * 100 + q * 4];
            #pragma unroll
            for (int r = 0; r < 5; r++) {
                float x = xl[(ty + 10 * r) * 100 + i];
                acc[r].x += x * w4.x; acc[r].y += x * w4.y;
                acc[r].z += x * w4.z; acc[r].w += x * w4.w;
            }
        }
        #pragma unroll
        for (int r = 0; r < 5; r++) {
            int n = c * 50 + ty + 10 * r;
            float sc = rowscale[b * NNODE + n];
            float4 o4 = make_float4(acc[r].x * sc, acc[r].y * sc, acc[r].z * sc, acc[r].w * sc);
            *(float4*)&Dst[n * 100 + q * 4] = o4;
        }
    }
}

// ---------------------------------------------------------------------------
// dvec1[b,g,n] = uni[b,g] * sum_f Dh0[b,f,n] * trans[b,f,g]
// rs0[b,n]    = end / (end * sum_f Dh0[b,f,n] + EPS)
__global__ void dmix_rs(const float* __restrict__ Dh0, const float* __restrict__ trans,
                        const float* __restrict__ uni, const float* __restrict__ endat,
                        float* __restrict__ dvec1, float* __restrict__ rs0) {
    int b = blockIdx.x;
    __shared__ float tl[NHEAD * NHEAD];
    for (int idx = threadIdx.x; idx < NHEAD * NHEAD; idx += 256) tl[idx] = trans[b * NHEAD * NHEAD + idx];
    __syncthreads();
    int n = threadIdx.x;
    if (n < NNODE) {
        float dh[NHEAD];
        float s = 0.f;
        #pragma unroll
        for (int f = 0; f < NHEAD; f++) { dh[f] = Dh0[((size_t)b * NHEAD + f) * NNODE + n]; s += dh[f]; }
        float e = endat[b * NNODE + n];
        rs0[b * NNODE + n] = e / (e * s + EPSV);
        #pragma unroll
        for (int g = 0; g < NHEAD; g++) {
            float acc = 0.f;
            #pragma unroll
            for (int f = 0; f < NHEAD; f++) acc += dh[f] * tl[f * NHEAD + g];
            dvec1[((size_t)b * NHEAD + g) * NNODE + n] = uni[b * NHEAD + g] * acc;
        }
    }
}

// ---------------------------------------------------------------------------
// Head mix + f-sum (float2/lane)
__global__ __launch_bounds__(256) void hmix(
    const float* __restrict__ Zsrc, const float* __restrict__ trans,
    float* __restrict__ Zdst, float* __restrict__ Zsum)
{
    int b = blockIdx.y;
    int c2 = blockIdx.x * 256 + threadIdx.x;   // float2 index, 10000 per b
    __shared__ __align__(8) float tl[NHEAD * NHEAD];
    for (int idx = threadIdx.x; idx < NHEAD * NHEAD; idx += 256) tl[idx] = trans[b * NHEAD * NHEAD + idx];
    __syncthreads();
    if (c2 >= 10000) return;
    const float2* Zb = (const float2*)(Zsrc + (size_t)b * NHEAD * 20000) + c2;
    float2 acc[NHEAD];
    #pragma unroll
    for (int g = 0; g < NHEAD; g++) acc[g] = make_float2(0.f, 0.f);
    float2 s = make_float2(0.f, 0.f);
    for (int f = 0; f < NHEAD; f++) {
        float2 vf = Zb[(size_t)f * 10000];
        s.x += vf.x; s.y += vf.y;
        const float2* row = (const float2*)&tl[f * NHEAD];
        #pragma unroll
        for (int gq = 0; gq < 17; gq++) {
            float2 t2 = row[gq];
            acc[2 * gq].x     += vf.x * t2.x; acc[2 * gq].y     += vf.y * t2.x;
            acc[2 * gq + 1].x += vf.x * t2.y; acc[2 * gq + 1].y += vf.y * t2.y;
        }
    }
    ((float2*)(Zsum + (size_t)b * 20000))[c2] = s;
    float2* Zd = (float2*)(Zdst + (size_t)b * NHEAD * 20000) + c2;
    #pragma unroll
    for (int g = 0; g < NHEAD; g++) Zd[(size_t)g * 10000] = acc[g];
}

// ---------------------------------------------------------------------------
// out1[b,n,i] = rs1[b,n] * sum_g Zacc[b,g,n,i]; rs1 computed inline from Dh1.
__global__ void fsum_out(const float* __restrict__ Zacc, const float* __restrict__ Dh1,
                         const float* __restrict__ endat, float* __restrict__ out) {
    int idx = blockIdx.x * 256 + threadIdx.x;   // float2 units
    if (idx >= NBATCH * 10000) return;
    int b = idx / 10000;
    int c2 = idx % 10000;
    const float2* Zb = (const float2*)(Zacc + (size_t)b * NHEAD * 20000) + c2;
    float2 s = make_float2(0.f, 0.f);
    #pragma unroll
    for (int g = 0; g < NHEAD; g++) {
        float2 v = Zb[(size_t)g * 10000];
        s.x += v.x; s.y += v.y;
    }
    int n = (c2 * 2) / 100;
    float ds = 0.f;
    #pragma unroll
    for (int f = 0; f < NHEAD; f++) ds += Dh1[((size_t)b * NHEAD + f) * NNODE + n];
    float e = endat[b * NNODE + n];
    float r = e / (e * ds + EPSV);
    s.x *= r; s.y *= r;
    ((float2*)out)[idx] = s;
}

// ---------------------------------------------------------------------------
extern "C" void kernel_launch(void* const* d_in, const int* in_sizes, int n_in,
                              void* d_out, int out_size, void* d_ws, size_t ws_size,
                              hipStream_t stream) {
    (void)in_sizes; (void)n_in;
    const float* X     = (const float*)d_in[0];
    const float* A     = (const float*)d_in[1];
    const float* start = (const float*)d_in[2];
    const float* endat = (const float*)d_in[3];
    const float* uni   = (const float*)d_in[4];
    const float* trans = (const float*)d_in[5];
    const float* wv    = (const float*)d_in[6];
    float* out = (float*)d_out;
    float* ws  = (float*)d_ws;

    size_t off = 0;
    unsigned long long* bm = (unsigned long long*)(ws); off += 1740800;  // 217600 rows * 4 u64
    float* buf1  = ws + off; off += 21760000;
    float* buf2  = ws + off; off += 21760000;
    float* Dh0   = ws + off; off += 217600;
    float* dvec1 = ws + off; off += 217600;
    float* Dh1   = ws + off; off += 217600;
    float* rs0   = ws + off; off += 6400;
    float* Zsum0 = ws + off; off += 640000;
    short* wfr   = (short*)(ws + off); off += 974848;   // 68*28*2*512 shorts
    short* xfr   = (short*)(ws + off); off += 851968;   // 32*52*2*512 shorts
    if (ws_size < off * sizeof(float)) {
        hipMemsetAsync(d_out, 0x7F, (size_t)out_size * sizeof(float), stream);
        return;
    }

    const float* Wi1 = wv + 690000;        // w_vs[1, 34]
    const short* wfr0 = wfr;
    const short* wfr1 = wfr + (size_t)34 * 28 * 2 * 512;
    const unsigned* bm32 = (const unsigned*)bm;

    dim3 gBF(NHEAD * 2, NBATCH);           // x = f*2 + col-half (pre-swizzle)

    // prepasses
    a_bitmask<<<(NBATCH * NHEAD * NNODE + 15) / 16, 1024, 0, stream>>>(A, bm);
    wx_split<<<100, 256, 0, stream>>>(wv, X, start, wfr, xfr);

    // t = 0 : fused W-GEMM + A-GEMM (dvec computed in-kernel)
    fused_zha<0><<<gBF, 1024, 0, stream>>>(bm32, xfr, nullptr, wfr0, uni, start, nullptr, buf2, Dh0);
    dmix_rs<<<NBATCH, 256, 0, stream>>>(Dh0, trans, uni, endat, dvec1, rs0);
    hmix<<<dim3(40, NBATCH), 256, 0, stream>>>(buf2, trans, buf1, Zsum0);    // buf1 = Zin1
    out0_gemm<<<dim3(4, NBATCH), 256, 0, stream>>>(Zsum0, Wi1, rs0, out);    // out[0]

    // t = 1
    fused_zha<1><<<gBF, 1024, 0, stream>>>(bm32, nullptr, buf1, wfr1, uni, nullptr, dvec1, buf2, Dh1);
    fsum_out<<<(NBATCH * 10000 + 255) / 256, 256, 0, stream>>>(buf2, Dh1, endat, out + 640000);
}